// Round 12
// baseline (164.079 us; speedup 1.0000x reference)
//
#include <hip/hip_runtime.h>

#define NPHI 64
#define NS 8
#define NK 16
#define BATCH 512

typedef __attribute__((__ext_vector_type__(2))) float v2f;

// v_pk_fma_f32 acc = p * b + acc, with op_sel/neg variants (validated on HW in R10).
#define PK_BL(acc, p, b)  asm("v_pk_fma_f32 %0, %1, %2, %0 op_sel:[0,0,0] op_sel_hi:[1,0,1]" : "+v"(acc) : "v"(p), "v"(b))   // acc += p * {b.x,b.x}
#define PK_BH(acc, p, b)  asm("v_pk_fma_f32 %0, %1, %2, %0 op_sel:[0,1,0] op_sel_hi:[1,1,1]" : "+v"(acc) : "v"(p), "v"(b))   // acc += p * {b.y,b.y}
#define PK_BLN(acc, p, b) asm("v_pk_fma_f32 %0, %1, %2, %0 op_sel:[0,0,0] op_sel_hi:[1,0,1] neg_lo:[0,1,0] neg_hi:[0,1,0]" : "+v"(acc) : "v"(p), "v"(b)) // acc += p * {-b.x,-b.x}
#define PK_X(acc, p, b)   asm("v_pk_fma_f32 %0, %1, %2, %0 op_sel:[1,1,0] op_sel_hi:[0,1,1] neg_lo:[1,0,0]" : "+v"(acc) : "v"(p), "v"(b))   // acc += {-p.y, p.x} * b.y
#define PK_XH(acc, p, b)  asm("v_pk_fma_f32 %0, %1, %2, %0 op_sel:[1,1,0] op_sel_hi:[0,1,1] neg_hi:[1,0,0]" : "+v"(acc) : "v"(p), "v"(b))   // acc += {p.y, -p.x} * b.y
#define PK_XLO(acc, p, b) asm("v_pk_fma_f32 %0, %1, %2, %0 op_sel:[1,0,0] op_sel_hi:[0,0,1] neg_hi:[1,0,0]" : "+v"(acc) : "v"(p), "v"(b))   // acc += {p.y, -p.x} * b.x

// Paired in-place Gauss-Jordan of TWO 8x8 complex matrices (lane = i*8+j):
// the two independent shfl chains interleave per pivot, hiding DS latency.
__device__ __forceinline__ void cinv8_pair(float& ar0, float& ai0,
                                           float& ar1, float& ai1, int lane) {
    const int i = lane >> 3, j = lane & 7;
#pragma unroll
    for (int p = 0; p < 8; ++p) {
        const float pr0 = __shfl(ar0, p * 9, 64);
        const float pi0 = __shfl(ai0, p * 9, 64);
        const float pr1 = __shfl(ar1, p * 9, 64);
        const float pi1 = __shfl(ai1, p * 9, 64);
        const float aipr0 = __shfl(ar0, (i << 3) | p, 64);
        const float aipi0 = __shfl(ai0, (i << 3) | p, 64);
        const float aipr1 = __shfl(ar1, (i << 3) | p, 64);
        const float aipi1 = __shfl(ai1, (i << 3) | p, 64);
        const float apjr0 = __shfl(ar0, (p << 3) | j, 64);
        const float apji0 = __shfl(ai0, (p << 3) | j, 64);
        const float apjr1 = __shfl(ar1, (p << 3) | j, 64);
        const float apji1 = __shfl(ai1, (p << 3) | j, 64);
        const bool ip = (i == p), jp = (j == p);
        {
            const float den = pr0 * pr0 + pi0 * pi0;
            const float rr = pr0 / den, ri = -pi0 / den;
            const float br = rr * apjr0 - ri * apji0;
            const float bi = rr * apji0 + ri * apjr0;
            const float er = ar0 - (aipr0 * br - aipi0 * bi);
            const float ei = ai0 - (aipr0 * bi + aipi0 * br);
            const float rowr = rr * ar0 - ri * ai0;
            const float rowi = rr * ai0 + ri * ar0;
            const float nr = ip ? (jp ? rr : rowr) : (jp ? -rowr : er);
            const float ni = ip ? (jp ? ri : rowi) : (jp ? -rowi : ei);
            ar0 = nr; ai0 = ni;
        }
        {
            const float den = pr1 * pr1 + pi1 * pi1;
            const float rr = pr1 / den, ri = -pi1 / den;
            const float br = rr * apjr1 - ri * apji1;
            const float bi = rr * apji1 + ri * apjr1;
            const float er = ar1 - (aipr1 * br - aipi1 * bi);
            const float ei = ai1 - (aipr1 * bi + aipi1 * br);
            const float rowr = rr * ar1 - ri * ai1;
            const float rowi = rr * ai1 + ri * ar1;
            const float nr = ip ? (jp ? rr : rowr) : (jp ? -rowr : er);
            const float ni = ip ? (jp ? ri : rowi) : (jp ? -rowi : ei);
            ar1 = nr; ai1 = ni;
        }
    }
}

// ONE WAVE handles TWO (k,b) problems (k0=2p, k1=2p+1, shared b) for 2-way
// ILP: independent chains interleave to hide load/shfl latency (the whole
// grid is co-resident, so kernel time == per-wave critical path).
// Phi loads shared between the two instances. No __syncthreads.
__global__ __launch_bounds__(256, 2) void k_grad_diag(
    const float* __restrict__ PhiR, const float* __restrict__ PhiI,
    const float* __restrict__ GhR, const float* __restrict__ GhI,
    const float* __restrict__ LamR, const float* __restrict__ LamI,
    const float* __restrict__ CR, const float* __restrict__ CI,
    const float* __restrict__ Beta,
    float* __restrict__ out, int region)
{
    const int tid = threadIdx.x;
    const int w = tid >> 6;          // wave id in block
    const int lane = tid & 63;
    const int gw = blockIdx.x * 4 + w;       // [0, 4096)
    const int b = gw >> 3;                   // [0, 512)
    const int kp = gw & 7;
    const int k0 = kp * 2, k1 = kp * 2 + 1;
    const int kb0 = k0 * BATCH + b;
    const int kb1 = k1 * BATCH + b;

    __shared__ float2 sM[4][2][NPHI][9];   // M^T per instance, 72B rows  36KB
    __shared__ float2 sQ2[4][2][64];       // Qi^2 per instance            4KB

    const float* phiR = PhiR + b * 4096;
    const float* phiI = PhiI + b * 4096;
    const float* ghR0 = GhR + kb0 * 512;
    const float* ghI0 = GhI + kb0 * 512;
    const float* ghR1 = GhR + kb1 * 512;
    const float* ghI1 = GhI + kb1 * 512;
    const float invb0 = 1.0f / Beta[kb0];
    const float invb1 = 1.0f / Beta[kb1];

    // M accumulators (live through S): a{0,1}r[sp]={mr[2sp],mr[2sp+1]}, a{0,1}i likewise
    v2f a0r[4], a0i[4], a1r[4], a1i[4];
    // T accumulators (live through S and d): acc2_{0,1}[s]={tr[s],ti[s]}
    v2f t0[8], t1[8];

    // ---- M[s,f] = sum_e conj(gh[e,s]) * phi[e,f] ; lane = f. Phi shared.
    {
#pragma unroll
        for (int sp = 0; sp < 4; ++sp) {
            a0r[sp] = (v2f)0.f; a0i[sp] = (v2f)0.f;
            a1r[sp] = (v2f)0.f; a1i[sp] = (v2f)0.f;
        }
        float pA[4], qA[4], pB[4], qB[4];
#pragma unroll
        for (int u = 0; u < 4; ++u) {
            pA[u] = phiR[u * 64 + lane];
            qA[u] = phiI[u * 64 + lane];
        }
#pragma unroll 1
        for (int eb = 0; eb < 64; eb += 8) {
#pragma unroll
            for (int u = 0; u < 4; ++u) {          // prefetch half B
                pB[u] = phiR[(eb + 4 + u) * 64 + lane];
                qB[u] = phiI[(eb + 4 + u) * 64 + lane];
            }
#pragma unroll
            for (int u = 0; u < 4; ++u) {          // compute half A, both insts
                const int e = eb + u;
                const v2f* g20 = (const v2f*)(ghR0 + e * 8);
                const v2f* h20 = (const v2f*)(ghI0 + e * 8);
                const v2f* g21 = (const v2f*)(ghR1 + e * 8);
                const v2f* h21 = (const v2f*)(ghI1 + e * 8);
                v2f pp; pp.x = pA[u]; pp.y = qA[u];
#pragma unroll
                for (int sp = 0; sp < 4; ++sp) {
                    const v2f g0 = g20[sp], h0 = h20[sp];
                    PK_BL(a0r[sp], g0, pp);  PK_BH(a0r[sp], h0, pp);
                    PK_BH(a0i[sp], g0, pp);  PK_BLN(a0i[sp], h0, pp);
                    const v2f g1 = g21[sp], h1 = h21[sp];
                    PK_BL(a1r[sp], g1, pp);  PK_BH(a1r[sp], h1, pp);
                    PK_BH(a1i[sp], g1, pp);  PK_BLN(a1i[sp], h1, pp);
                }
            }
            if (eb + 8 < 64) {
#pragma unroll
                for (int u = 0; u < 4; ++u) {      // prefetch next half A
                    pA[u] = phiR[(eb + 8 + u) * 64 + lane];
                    qA[u] = phiI[(eb + 8 + u) * 64 + lane];
                }
            }
#pragma unroll
            for (int u = 0; u < 4; ++u) {          // compute half B, both insts
                const int e = eb + 4 + u;
                const v2f* g20 = (const v2f*)(ghR0 + e * 8);
                const v2f* h20 = (const v2f*)(ghI0 + e * 8);
                const v2f* g21 = (const v2f*)(ghR1 + e * 8);
                const v2f* h21 = (const v2f*)(ghI1 + e * 8);
                v2f pp; pp.x = pB[u]; pp.y = qB[u];
#pragma unroll
                for (int sp = 0; sp < 4; ++sp) {
                    const v2f g0 = g20[sp], h0 = h20[sp];
                    PK_BL(a0r[sp], g0, pp);  PK_BH(a0r[sp], h0, pp);
                    PK_BH(a0i[sp], g0, pp);  PK_BLN(a0i[sp], h0, pp);
                    const v2f g1 = g21[sp], h1 = h21[sp];
                    PK_BL(a1r[sp], g1, pp);  PK_BH(a1r[sp], h1, pp);
                    PK_BH(a1i[sp], g1, pp);  PK_BLN(a1i[sp], h1, pp);
                }
            }
        }
#pragma unroll
        for (int sp = 0; sp < 4; ++sp) {
            sM[w][0][lane][2 * sp]     = make_float2(a0r[sp].x, a0i[sp].x);
            sM[w][0][lane][2 * sp + 1] = make_float2(a0r[sp].y, a0i[sp].y);
            sM[w][1][lane][2 * sp]     = make_float2(a1r[sp].x, a1i[sp].x);
            sM[w][1][lane][2 * sp + 1] = make_float2(a1r[sp].y, a1i[sp].y);
        }
    }

    // ---- T[s,g] = sum_f M[s,f]*C[f,g] ; lane = g. Two C streams, 2-row halves.
    {
        const float* cR0 = CR + (size_t)kb0 * 4096;
        const float* cI0 = CI + (size_t)kb0 * 4096;
        const float* cR1 = CR + (size_t)kb1 * 4096;
        const float* cI1 = CI + (size_t)kb1 * 4096;
#pragma unroll
        for (int s = 0; s < 8; ++s) { t0[s] = (v2f)0.f; t1[s] = (v2f)0.f; }
        float c0A[2], d0A[2], c1A[2], d1A[2];
        float c0B[2], d0B[2], c1B[2], d1B[2];
#pragma unroll
        for (int u = 0; u < 2; ++u) {
            c0A[u] = cR0[u * 64 + lane];  d0A[u] = cI0[u * 64 + lane];
            c1A[u] = cR1[u * 64 + lane];  d1A[u] = cI1[u * 64 + lane];
        }
#pragma unroll 1
        for (int fb = 0; fb < 64; fb += 4) {
#pragma unroll
            for (int u = 0; u < 2; ++u) {          // prefetch half B (rows fb+2,3)
                c0B[u] = cR0[(fb + 2 + u) * 64 + lane];  d0B[u] = cI0[(fb + 2 + u) * 64 + lane];
                c1B[u] = cR1[(fb + 2 + u) * 64 + lane];  d1B[u] = cI1[(fb + 2 + u) * 64 + lane];
            }
#pragma unroll
            for (int u = 0; u < 2; ++u) {          // compute half A (rows fb,fb+1)
                const int f = fb + u;
                const v2f* m0 = (const v2f*)(&sM[w][0][f][0]);  // broadcast
                const v2f* m1 = (const v2f*)(&sM[w][1][f][0]);
                v2f cc0; cc0.x = c0A[u]; cc0.y = d0A[u];
                v2f cc1; cc1.x = c1A[u]; cc1.y = d1A[u];
#pragma unroll
                for (int s = 0; s < 8; ++s) {
                    const v2f ms0 = m0[s];
                    PK_BL(t0[s], cc0, ms0);  PK_X(t0[s], cc0, ms0);
                    const v2f ms1 = m1[s];
                    PK_BL(t1[s], cc1, ms1);  PK_X(t1[s], cc1, ms1);
                }
            }
            if (fb + 4 < 64) {
#pragma unroll
                for (int u = 0; u < 2; ++u) {      // prefetch next half A
                    c0A[u] = cR0[(fb + 4 + u) * 64 + lane];  d0A[u] = cI0[(fb + 4 + u) * 64 + lane];
                    c1A[u] = cR1[(fb + 4 + u) * 64 + lane];  d1A[u] = cI1[(fb + 4 + u) * 64 + lane];
                }
            }
#pragma unroll
            for (int u = 0; u < 2; ++u) {          // compute half B
                const int f = fb + 2 + u;
                const v2f* m0 = (const v2f*)(&sM[w][0][f][0]);
                const v2f* m1 = (const v2f*)(&sM[w][1][f][0]);
                v2f cc0; cc0.x = c0B[u]; cc0.y = d0B[u];
                v2f cc1; cc1.x = c1B[u]; cc1.y = d1B[u];
#pragma unroll
                for (int s = 0; s < 8; ++s) {
                    const v2f ms0 = m0[s];
                    PK_BL(t0[s], cc0, ms0);  PK_X(t0[s], cc0, ms0);
                    const v2f ms1 = m1[s];
                    PK_BL(t1[s], cc1, ms1);  PK_X(t1[s], cc1, ms1);
                }
            }
        }
    }

    // Lam loads issued early (hide under butterfly)
    const float lr0 = LamR[kb0 * 64 + lane], li0 = LamI[kb0 * 64 + lane];
    const float lr1 = LamR[kb1 * 64 + lane], li1 = LamI[kb1 * 64 + lane];

    // ---- S = T M^H / beta via register reduce-scatter butterfly, both insts
    // interleaved per stage (chains hide each other's shfl latency).
    float sre0, sim0, sre1, sim1;
    {
        const bool l0 = (lane & 1) != 0;
        const bool l1 = (lane & 2) != 0;
        const bool l2 = (lane & 4) != 0;
        v2f Sv0 = (v2f)0.f, Sv1 = (v2f)0.f;
#pragma unroll
        for (int s = 0; s < 8; ++s) {
            v2f p0[8], p1[8];
#pragma unroll
            for (int t = 0; t < 8; ++t) {
                v2f acc = (v2f)0.f;
                const v2f mre = a0r[t >> 1], mim = a0i[t >> 1];
                if (t & 1) { PK_BH(acc, t0[s], mre); PK_XH(acc, t0[s], mim); }
                else       { PK_BL(acc, t0[s], mre); PK_XLO(acc, t0[s], mim); }
                p0[t] = acc;
                v2f acd = (v2f)0.f;
                const v2f nre = a1r[t >> 1], nim = a1i[t >> 1];
                if (t & 1) { PK_BH(acd, t1[s], nre); PK_XH(acd, t1[s], nim); }
                else       { PK_BL(acd, t1[s], nre); PK_XLO(acd, t1[s], nim); }
                p1[t] = acd;
            }
            v2f q0[4], q1[4];
#pragma unroll
            for (int j = 0; j < 4; ++j) {
                v2f snd = l0 ? p0[2 * j] : p0[2 * j + 1];
                v2f kp  = l0 ? p0[2 * j + 1] : p0[2 * j];
                kp.x += __shfl_xor(snd.x, 1, 64);
                kp.y += __shfl_xor(snd.y, 1, 64);
                q0[j] = kp;
                v2f snd1 = l0 ? p1[2 * j] : p1[2 * j + 1];
                v2f kp1  = l0 ? p1[2 * j + 1] : p1[2 * j];
                kp1.x += __shfl_xor(snd1.x, 1, 64);
                kp1.y += __shfl_xor(snd1.y, 1, 64);
                q1[j] = kp1;
            }
            v2f r0[2], r1[2];
#pragma unroll
            for (int m = 0; m < 2; ++m) {
                v2f snd = l1 ? q0[2 * m] : q0[2 * m + 1];
                v2f kp  = l1 ? q0[2 * m + 1] : q0[2 * m];
                kp.x += __shfl_xor(snd.x, 2, 64);
                kp.y += __shfl_xor(snd.y, 2, 64);
                r0[m] = kp;
                v2f snd1 = l1 ? q1[2 * m] : q1[2 * m + 1];
                v2f kp1  = l1 ? q1[2 * m + 1] : q1[2 * m];
                kp1.x += __shfl_xor(snd1.x, 2, 64);
                kp1.y += __shfl_xor(snd1.y, 2, 64);
                r1[m] = kp1;
            }
            v2f s0 = l2 ? r0[0] : r0[1];
            v2f v0 = l2 ? r0[1] : r0[0];
            v0.x += __shfl_xor(s0.x, 4, 64);
            v0.y += __shfl_xor(s0.y, 4, 64);
            v2f s1 = l2 ? r1[0] : r1[1];
            v2f v1 = l2 ? r1[1] : r1[0];
            v1.x += __shfl_xor(s1.x, 4, 64);
            v1.y += __shfl_xor(s1.y, 4, 64);
            v0.x += __shfl_xor(v0.x, 8, 64);  v0.y += __shfl_xor(v0.y, 8, 64);
            v1.x += __shfl_xor(v1.x, 8, 64);  v1.y += __shfl_xor(v1.y, 8, 64);
            v0.x += __shfl_xor(v0.x, 16, 64); v0.y += __shfl_xor(v0.y, 16, 64);
            v1.x += __shfl_xor(v1.x, 16, 64); v1.y += __shfl_xor(v1.y, 16, 64);
            v0.x += __shfl_xor(v0.x, 32, 64); v0.y += __shfl_xor(v0.y, 32, 64);
            v1.x += __shfl_xor(v1.x, 32, 64); v1.y += __shfl_xor(v1.y, 32, 64);
            Sv0 = ((lane >> 3) == s) ? v0 : Sv0;
            Sv1 = ((lane >> 3) == s) ? v1 : Sv1;
        }
        sre0 = Sv0.x * invb0; sim0 = Sv0.y * invb0;
        sre1 = Sv1.x * invb1; sim1 = Sv1.y * invb1;
    }

    // ---- Q = inv(Lam)+S ; Qi = inv(Q); Qi2 = Qi@Qi, both instances paired
    {
        float ar0 = lr0, ai0 = li0, ar1 = lr1, ai1 = li1;
        cinv8_pair(ar0, ai0, ar1, ai1, lane);
        ar0 += sre0; ai0 += sim0;
        ar1 += sre1; ai1 += sim1;
        cinv8_pair(ar0, ai0, ar1, ai1, lane);
        const int i = lane >> 3, j = lane & 7;
        float q0r = 0.f, q0i = 0.f, q1r = 0.f, q1i = 0.f;
#pragma unroll
        for (int t = 0; t < 8; ++t) {
            const float x0r = __shfl(ar0, (i << 3) | t, 64);
            const float x0i = __shfl(ai0, (i << 3) | t, 64);
            const float y0r = __shfl(ar0, (t << 3) | j, 64);
            const float y0i = __shfl(ai0, (t << 3) | j, 64);
            const float x1r = __shfl(ar1, (i << 3) | t, 64);
            const float x1i = __shfl(ai1, (i << 3) | t, 64);
            const float y1r = __shfl(ar1, (t << 3) | j, 64);
            const float y1i = __shfl(ai1, (t << 3) | j, 64);
            q0r += x0r * y0r - x0i * y0i;
            q0i += x0r * y0i + x0i * y0r;
            q1r += x1r * y1r - x1i * y1i;
            q1i += x1r * y1i + x1i * y1r;
        }
        sQ2[w][0][lane] = make_float2(q0r, q0i);
        sQ2[w][1][lane] = make_float2(q1r, q1i);
    }

    // ---- d[f] = (sum_s gh[f,s] * sum_t Qi2[s,t]*T[t,f]) / beta ; lane = f
    {
        const float4 a0 = *(const float4*)(ghR0 + lane * 8);   // L1-hot
        const float4 a1 = *(const float4*)(ghR0 + lane * 8 + 4);
        const float4 c0 = *(const float4*)(ghI0 + lane * 8);
        const float4 c1 = *(const float4*)(ghI0 + lane * 8 + 4);
        const float gfr[8] = {a0.x, a0.y, a0.z, a0.w, a1.x, a1.y, a1.z, a1.w};
        const float gfi[8] = {c0.x, c0.y, c0.z, c0.w, c1.x, c1.y, c1.z, c1.w};
        float dre = 0.f, dim = 0.f;
#pragma unroll
        for (int s = 0; s < 8; ++s) {
            float yr = 0.f, yi = 0.f;
#pragma unroll
            for (int t = 0; t < 8; ++t) {
                const float2 q = sQ2[w][0][s * 8 + t];   // broadcast
                yr += q.x * t0[t].x - q.y * t0[t].y;
                yi += q.x * t0[t].y + q.y * t0[t].x;
            }
            dre += gfr[s] * yr - gfi[s] * yi;
            dim += gfr[s] * yi + gfi[s] * yr;
        }
        float2* scr0 = (float2*)(out + (size_t)b * region + k0 * 128);
        scr0[lane] = make_float2(dre * invb0, dim * invb0);

        const float4 e0 = *(const float4*)(ghR1 + lane * 8);
        const float4 e1 = *(const float4*)(ghR1 + lane * 8 + 4);
        const float4 f0 = *(const float4*)(ghI1 + lane * 8);
        const float4 f1 = *(const float4*)(ghI1 + lane * 8 + 4);
        const float hfr[8] = {e0.x, e0.y, e0.z, e0.w, e1.x, e1.y, e1.z, e1.w};
        const float hfi[8] = {f0.x, f0.y, f0.z, f0.w, f1.x, f1.y, f1.z, f1.w};
        float er = 0.f, ei = 0.f;
#pragma unroll
        for (int s = 0; s < 8; ++s) {
            float yr = 0.f, yi = 0.f;
#pragma unroll
            for (int t = 0; t < 8; ++t) {
                const float2 q = sQ2[w][1][s * 8 + t];
                yr += q.x * t1[t].x - q.y * t1[t].y;
                yi += q.x * t1[t].y + q.y * t1[t].x;
            }
            er += hfr[s] * yr - hfi[s] * yi;
            ei += hfr[s] * yi + hfi[s] * yr;
        }
        float2* scr1 = (float2*)(out + (size_t)b * region + k1 * 128);
        scr1[lane] = make_float2(er * invb1, ei * invb1);
    }
}

// One block per b: step-size NN, diagonal Riemannian update, clamp, store.
// Reads own-region scratch (front 2048 floats) before overwriting the region.
__global__ __launch_bounds__(256) void k_finalize(
    const float* __restrict__ PhiR, const float* __restrict__ PhiI,
    const float* __restrict__ bnG, const float* __restrict__ bnB,
    const float* __restrict__ bnM, const float* __restrict__ bnV,
    const float* __restrict__ W, const float* __restrict__ Bb,
    float* __restrict__ out, int region, int cplx)
{
    const int b = blockIdx.x;
    const int tid = threadIdx.x;
    __shared__ float sIQ[128];
    __shared__ float sRed[2];
    __shared__ float sDre[64], sDim[64];

    const float* phiR = PhiR + b * 4096;
    const float* phiI = PhiI + b * 4096;
    float* outp = out + (size_t)b * region;

    // diagonal eg sum over k from own-region scratch (read BEFORE any writes)
    float er = 0.f, ei = 0.f;
    if (tid < 64) {
        const int f = tid;
#pragma unroll
        for (int kk = 0; kk < NK; ++kk) {
            const float2 dv = ((const float2*)(outp + kk * 128))[f];
            er += dv.x; ei += dv.y;
        }
    }

    // row sums of Phi (Phi @ ones): 4 threads per row
    {
        const int r = tid >> 2, pq = tid & 3;
        float sr = 0.f, si = 0.f;
        const float4* a4 = (const float4*)(phiR + r * 64 + pq * 16);
        const float4* c4 = (const float4*)(phiI + r * 64 + pq * 16);
#pragma unroll
        for (int q = 0; q < 4; ++q) {
            const float4 a = a4[q]; sr += (a.x + a.y) + (a.z + a.w);
            const float4 c = c4[q]; si += (c.x + c.y) + (c.z + c.w);
        }
        sr += __shfl_xor(sr, 1, 64); si += __shfl_xor(si, 1, 64);
        sr += __shfl_xor(sr, 2, 64); si += __shfl_xor(si, 2, 64);
        if (pq == 0) { sIQ[r] = sr; sIQ[64 + r] = si; }
    }
    __syncthreads();

    // BN -> Dense(1) -> leaky_relu
    if (tid < 128) {
        const float v = sIQ[tid];
        const float t = bnG[tid] * (v - bnM[tid]) * rsqrtf(bnV[tid] + 1e-3f) + bnB[tid];
        float contrib = t * W[tid];
#pragma unroll
        for (int o = 1; o < 64; o <<= 1) contrib += __shfl_xor(contrib, o, 64);
        if ((tid & 63) == 0) sRed[tid >> 6] = contrib;
    }
    __syncthreads();
    const float s_lin = sRed[0] + sRed[1] + Bb[0];
    const float step = (s_lin >= 0.f) ? s_lin : 0.1f * s_lin;

    // diagonal Riemannian gradient + norm (rg is exactly 0 off-diagonal)
    if (tid < 64) {
        const int f = tid;
        er *= -(1.0f / NK); ei *= -(1.0f / NK);
        const float prr = phiR[f * 65];
        const float pii = phiI[f * 65];
        const float proj = er * prr + ei * pii;     // Re(eg * conj(Phi))
        const float rr = er - proj * prr;
        const float ri = ei - proj * pii;
        float n2 = rr * rr + ri * ri;
#pragma unroll
        for (int o = 1; o < 64; o <<= 1) n2 += __shfl_xor(n2, o, 64);
        const float sc = step / sqrtf(n2);
        sDre[f] = sc * rr;
        sDim[f] = sc * ri;
    }
    __syncthreads();   // all scratch reads done; safe to overwrite region

    // elementwise: subtract diag update, magnitude clamp, store
#pragma unroll
    for (int p = 0; p < 4; ++p) {
        const int base = p * 1024 + tid * 4;
        const float4 a = *(const float4*)(phiR + base);
        const float4 c = *(const float4*)(phiI + base);
        const int row = base >> 6;
        const int col0 = base & 63;
        float re[4] = {a.x, a.y, a.z, a.w};
        float im[4] = {c.x, c.y, c.z, c.w};
#pragma unroll
        for (int q = 0; q < 4; ++q) {
            if (row == col0 + q) { re[q] -= sDre[row]; im[q] -= sDim[row]; }
            const float ab = sqrtf(re[q] * re[q] + im[q] * im[q]);
            const float den = fmaxf(ab - 1.f, 0.f) + 1.f;
            re[q] /= den; im[q] /= den;
        }
        if (cplx) {
            *(float4*)(outp + base * 2)     = make_float4(re[0], im[0], re[1], im[1]);
            *(float4*)(outp + base * 2 + 4) = make_float4(re[2], im[2], re[3], im[3]);
        } else {
            *(float4*)(outp + base) = make_float4(re[0], re[1], re[2], re[3]);
        }
    }
}

extern "C" void kernel_launch(void* const* d_in, const int* in_sizes, int n_in,
                              void* d_out, int out_size, void* d_ws, size_t ws_size,
                              hipStream_t stream) {
    const float* PhiR = (const float*)d_in[0];
    const float* PhiI = (const float*)d_in[1];
    const float* GhR  = (const float*)d_in[2];
    const float* GhI  = (const float*)d_in[3];
    const float* LamR = (const float*)d_in[4];
    const float* LamI = (const float*)d_in[5];
    const float* CR   = (const float*)d_in[6];
    const float* CI   = (const float*)d_in[7];
    const float* Beta = (const float*)d_in[8];
    const float* bnG  = (const float*)d_in[9];
    const float* bnB  = (const float*)d_in[10];
    const float* bnM  = (const float*)d_in[11];
    const float* bnV  = (const float*)d_in[12];
    const float* W    = (const float*)d_in[13];
    const float* Bb   = (const float*)d_in[14];
    float* outp = (float*)d_out;

    // out_size == B*64*64  -> real-part-only float32 layout
    // out_size == B*64*64*2 -> interleaved complex64 layout
    const int cplx = (out_size >= 3000000) ? 1 : 0;
    const int region = cplx ? 8192 : 4096;

    k_grad_diag<<<(NK * BATCH) / 8, 256, 0, stream>>>(PhiR, PhiI, GhR, GhI,
                                                      LamR, LamI, CR, CI, Beta,
                                                      outp, region);
    k_finalize<<<BATCH, 256, 0, stream>>>(PhiR, PhiI,
                                          bnG, bnB, bnM, bnV, W, Bb,
                                          outp, region, cplx);
}

// Round 13
// 133.927 us; speedup vs baseline: 1.2251x; 1.2251x over previous
//
#include <hip/hip_runtime.h>

#define NPHI 64
#define NS 8
#define NK 16
#define BATCH 512

typedef __attribute__((__ext_vector_type__(2))) float v2f;

// v_pk_fma_f32 acc = p * b + acc, with op_sel/neg variants (validated on HW in R10).
#define PK_BL(acc, p, b)  asm("v_pk_fma_f32 %0, %1, %2, %0 op_sel:[0,0,0] op_sel_hi:[1,0,1]" : "+v"(acc) : "v"(p), "v"(b))   // acc += p * {b.x,b.x}
#define PK_BH(acc, p, b)  asm("v_pk_fma_f32 %0, %1, %2, %0 op_sel:[0,1,0] op_sel_hi:[1,1,1]" : "+v"(acc) : "v"(p), "v"(b))   // acc += p * {b.y,b.y}
#define PK_BLN(acc, p, b) asm("v_pk_fma_f32 %0, %1, %2, %0 op_sel:[0,0,0] op_sel_hi:[1,0,1] neg_lo:[0,1,0] neg_hi:[0,1,0]" : "+v"(acc) : "v"(p), "v"(b)) // acc += p * {-b.x,-b.x}
#define PK_X(acc, p, b)   asm("v_pk_fma_f32 %0, %1, %2, %0 op_sel:[1,1,0] op_sel_hi:[0,1,1] neg_lo:[1,0,0]" : "+v"(acc) : "v"(p), "v"(b))   // acc += {-p.y, p.x} * b.y
#define PK_XH(acc, p, b)  asm("v_pk_fma_f32 %0, %1, %2, %0 op_sel:[1,1,0] op_sel_hi:[0,1,1] neg_hi:[1,0,0]" : "+v"(acc) : "v"(p), "v"(b))   // acc += {p.y, -p.x} * b.y
#define PK_XLO(acc, p, b) asm("v_pk_fma_f32 %0, %1, %2, %0 op_sel:[1,0,0] op_sel_hi:[0,0,1] neg_hi:[1,0,0]" : "+v"(acc) : "v"(p), "v"(b))   // acc += {p.y, -p.x} * b.x

// In-place Gauss-Jordan (sweep-operator) inversion of an 8x8 complex matrix
// held one element per lane (lane = i*8+j). No pivoting: HPD input.
__device__ __forceinline__ void cinv8(float& ar, float& ai, int lane) {
    const int i = lane >> 3, j = lane & 7;
#pragma unroll
    for (int p = 0; p < 8; ++p) {
        const float pr = __shfl(ar, p * 9, 64);
        const float pi = __shfl(ai, p * 9, 64);
        const float den = pr * pr + pi * pi;
        const float rr = pr / den, ri = -pi / den;           // r = 1/pivot
        const float aipr = __shfl(ar, (i << 3) | p, 64);
        const float aipi = __shfl(ai, (i << 3) | p, 64);
        const float apjr = __shfl(ar, (p << 3) | j, 64);
        const float apji = __shfl(ai, (p << 3) | j, 64);
        const float br = rr * apjr - ri * apji;              // r*a[p][j]
        const float bi = rr * apji + ri * apjr;
        const float er = ar - (aipr * br - aipi * bi);       // eliminate
        const float ei = ai - (aipr * bi + aipi * br);
        const float rowr = rr * ar - ri * ai;                // pivot row/col
        const float rowi = rr * ai + ri * ar;
        const bool ip = (i == p), jp = (j == p);
        const float nr = ip ? (jp ? rr : rowr) : (jp ? -rowr : er);
        const float ni = ip ? (jp ? ri : rowi) : (jp ? -rowi : ei);
        ar = nr; ai = ni;
    }
}

// ONE WAVE per (k,b); 4 independent waves per block; no __syncthreads.
// R11 structure (best: 138.5us) with ONE change: T-phase (the C stream, the
// only true HBM stream) ping-pong deepened 4->8 rows/half; Lam hoisted above
// the S butterfly. M-phase stays depth 4 (Phi is L2/L3-hot).
__global__ __launch_bounds__(256, 2) void k_grad_diag(
    const float* __restrict__ PhiR, const float* __restrict__ PhiI,
    const float* __restrict__ GhR, const float* __restrict__ GhI,
    const float* __restrict__ LamR, const float* __restrict__ LamI,
    const float* __restrict__ CR, const float* __restrict__ CI,
    const float* __restrict__ Beta,
    float* __restrict__ out, int region)
{
    const int tid = threadIdx.x;
    const int w = tid >> 6;          // wave id in block
    const int lane = tid & 63;
    const int gw = blockIdx.x * 4 + w;
    const int k = gw & (NK - 1);     // 4 waves of a block share b -> share Phi in L1
    const int b = gw >> 4;
    const int kb = k * BATCH + b;

    __shared__ __align__(16) float2 sM[4][NPHI][10];  // M^T: sM[w][f][s] = M[s,f]  20KB
    __shared__ float2 sQ2[4][64];                     // Qi^2, lane=(s*8+t)          2KB

    const float* phiR = PhiR + b * 4096;
    const float* phiI = PhiI + b * 4096;
    const float* ghR = GhR + kb * 512;
    const float* ghI = GhI + kb * 512;
    const float invb = 1.0f / Beta[kb];

    // M accumulators (kept live through S)
    v2f accr[4], acci[4];
    // T accumulators (kept live through S and d)
    v2f acc2[8];

    // ---- M[s,f] = sum_e conj(gh[e,s]) * phi[e,f] ; lane = f (depth-4 pipeline)
    {
#pragma unroll
        for (int sp = 0; sp < 4; ++sp) { accr[sp] = (v2f)0.f; acci[sp] = (v2f)0.f; }
        float pA[4], qA[4], pB[4], qB[4];
#pragma unroll
        for (int u = 0; u < 4; ++u) {
            pA[u] = phiR[u * 64 + lane];
            qA[u] = phiI[u * 64 + lane];
        }
#pragma unroll 1
        for (int eb = 0; eb < 64; eb += 8) {
#pragma unroll
            for (int u = 0; u < 4; ++u) {          // prefetch half B
                pB[u] = phiR[(eb + 4 + u) * 64 + lane];
                qB[u] = phiI[(eb + 4 + u) * 64 + lane];
            }
#pragma unroll
            for (int u = 0; u < 4; ++u) {          // compute half A
                const int e = eb + u;
                const v2f* g2 = (const v2f*)(ghR + e * 8);
                const v2f* h2 = (const v2f*)(ghI + e * 8);
                v2f pp; pp.x = pA[u]; pp.y = qA[u];
#pragma unroll
                for (int sp = 0; sp < 4; ++sp) {
                    const v2f g = g2[sp];
                    const v2f h = h2[sp];
                    PK_BL(accr[sp], g, pp);        // mr += gr*pr
                    PK_BH(accr[sp], h, pp);        // mr += gi*pi
                    PK_BH(acci[sp], g, pp);        // mi += gr*pi
                    PK_BLN(acci[sp], h, pp);       // mi -= gi*pr
                }
            }
            if (eb + 8 < 64) {
#pragma unroll
                for (int u = 0; u < 4; ++u) {      // prefetch next half A
                    pA[u] = phiR[(eb + 8 + u) * 64 + lane];
                    qA[u] = phiI[(eb + 8 + u) * 64 + lane];
                }
            }
#pragma unroll
            for (int u = 0; u < 4; ++u) {          // compute half B
                const int e = eb + 4 + u;
                const v2f* g2 = (const v2f*)(ghR + e * 8);
                const v2f* h2 = (const v2f*)(ghI + e * 8);
                v2f pp; pp.x = pB[u]; pp.y = qB[u];
#pragma unroll
                for (int sp = 0; sp < 4; ++sp) {
                    const v2f g = g2[sp];
                    const v2f h = h2[sp];
                    PK_BL(accr[sp], g, pp);
                    PK_BH(accr[sp], h, pp);
                    PK_BH(acci[sp], g, pp);
                    PK_BLN(acci[sp], h, pp);
                }
            }
        }
#pragma unroll
        for (int sp = 0; sp < 4; ++sp) {
            sM[w][lane][2 * sp]     = make_float2(accr[sp].x, acci[sp].x);
            sM[w][lane][2 * sp + 1] = make_float2(accr[sp].y, acci[sp].y);
        }
    }

    // ---- T[s,g] = sum_f M[s,f]*C[f,g] ; lane = g. DEPTH-8 pipeline on the
    // C stream (the HBM-latency-critical one): 16 loads in flight per wave.
    {
        const float* cR = CR + (size_t)kb * 4096;
        const float* cI = CI + (size_t)kb * 4096;
#pragma unroll
        for (int s = 0; s < 8; ++s) acc2[s] = (v2f)0.f;
        float pA[8], qA[8], pB[8], qB[8];
#pragma unroll
        for (int u = 0; u < 8; ++u) {
            pA[u] = cR[u * 64 + lane];
            qA[u] = cI[u * 64 + lane];
        }
#pragma unroll 1
        for (int fb = 0; fb < 64; fb += 16) {
#pragma unroll
            for (int u = 0; u < 8; ++u) {          // prefetch block B
                pB[u] = cR[(fb + 8 + u) * 64 + lane];
                qB[u] = cI[(fb + 8 + u) * 64 + lane];
            }
#pragma unroll
            for (int u = 0; u < 8; ++u) {          // compute block A
                const int f = fb + u;
                const v2f* mrow = (const v2f*)(&sM[w][f][0]);  // broadcast reads
                v2f cc; cc.x = pA[u]; cc.y = qA[u];
#pragma unroll
                for (int s = 0; s < 8; ++s) {
                    const v2f ms = mrow[s];
                    PK_BL(acc2[s], cc, ms);        // += Mr*{cr,ci}
                    PK_X(acc2[s], cc, ms);         // += Mi*{-ci,cr}
                }
            }
            if (fb + 16 < 64) {
#pragma unroll
                for (int u = 0; u < 8; ++u) {      // prefetch next block A
                    pA[u] = cR[(fb + 16 + u) * 64 + lane];
                    qA[u] = cI[(fb + 16 + u) * 64 + lane];
                }
            }
#pragma unroll
            for (int u = 0; u < 8; ++u) {          // compute block B
                const int f = fb + 8 + u;
                const v2f* mrow = (const v2f*)(&sM[w][f][0]);
                v2f cc; cc.x = pB[u]; cc.y = qB[u];
#pragma unroll
                for (int s = 0; s < 8; ++s) {
                    const v2f ms = mrow[s];
                    PK_BL(acc2[s], cc, ms);
                    PK_X(acc2[s], cc, ms);
                }
            }
        }
    }

    // Lam loads hoisted: latency hides under the S butterfly
    const float lamr = LamR[kb * 64 + lane];
    const float lami = LamI[kb * 64 + lane];

    // ---- S[s,t] = (sum_g T[s,g]*conj(M[t,g])) / beta via register butterfly.
    float sre, sim;
    {
        const bool l0 = (lane & 1) != 0;
        const bool l1 = (lane & 2) != 0;
        const bool l2 = (lane & 4) != 0;
        v2f Sv = (v2f)0.f;
#pragma unroll
        for (int s = 0; s < 8; ++s) {
            v2f p[8];
#pragma unroll
            for (int t = 0; t < 8; ++t) {
                v2f acc = (v2f)0.f;
                const v2f mre = accr[t >> 1];
                const v2f mim = acci[t >> 1];
                if (t & 1) { PK_BH(acc, acc2[s], mre); PK_XH(acc, acc2[s], mim); }
                else       { PK_BL(acc, acc2[s], mre); PK_XLO(acc, acc2[s], mim); }
                p[t] = acc;
            }
            v2f q[4];
#pragma unroll
            for (int j = 0; j < 4; ++j) {
                v2f snd = l0 ? p[2 * j] : p[2 * j + 1];
                v2f kp  = l0 ? p[2 * j + 1] : p[2 * j];
                kp.x += __shfl_xor(snd.x, 1, 64);
                kp.y += __shfl_xor(snd.y, 1, 64);
                q[j] = kp;
            }
            v2f r[2];
#pragma unroll
            for (int m = 0; m < 2; ++m) {
                v2f snd = l1 ? q[2 * m] : q[2 * m + 1];
                v2f kp  = l1 ? q[2 * m + 1] : q[2 * m];
                kp.x += __shfl_xor(snd.x, 2, 64);
                kp.y += __shfl_xor(snd.y, 2, 64);
                r[m] = kp;
            }
            v2f snd = l2 ? r[0] : r[1];
            v2f v   = l2 ? r[1] : r[0];
            v.x += __shfl_xor(snd.x, 4, 64);
            v.y += __shfl_xor(snd.y, 4, 64);
            v.x += __shfl_xor(v.x, 8, 64);  v.y += __shfl_xor(v.y, 8, 64);
            v.x += __shfl_xor(v.x, 16, 64); v.y += __shfl_xor(v.y, 16, 64);
            v.x += __shfl_xor(v.x, 32, 64); v.y += __shfl_xor(v.y, 32, 64);
            Sv = ((lane >> 3) == s) ? v : Sv;
        }
        sre = Sv.x * invb; sim = Sv.y * invb;
    }

    // ---- Q = inv(Lam) + S ; Qi = inv(Q); Qi2 = Qi@Qi   (lane = i*8+j)
    {
        float ar = lamr, ai = lami;
        cinv8(ar, ai, lane);
        ar += sre; ai += sim;
        cinv8(ar, ai, lane);
        const int i = lane >> 3, j = lane & 7;
        float qr = 0.f, qi = 0.f;
#pragma unroll
        for (int t = 0; t < 8; ++t) {
            const float xr = __shfl(ar, (i << 3) | t, 64);
            const float xi = __shfl(ai, (i << 3) | t, 64);
            const float yr = __shfl(ar, (t << 3) | j, 64);
            const float yi = __shfl(ai, (t << 3) | j, 64);
            qr += xr * yr - xi * yi;
            qi += xr * yi + xi * yr;
        }
        sQ2[w][lane] = make_float2(qr, qi);
    }

    // ---- d[f] = (sum_s gh[f,s] * sum_t Qi2[s,t]*T[t,f]) / beta ; lane = f
    {
        const float4 a0 = *(const float4*)(ghR + lane * 8);   // L1-hot
        const float4 a1 = *(const float4*)(ghR + lane * 8 + 4);
        const float4 c0 = *(const float4*)(ghI + lane * 8);
        const float4 c1 = *(const float4*)(ghI + lane * 8 + 4);
        const float gfr[8] = {a0.x, a0.y, a0.z, a0.w, a1.x, a1.y, a1.z, a1.w};
        const float gfi[8] = {c0.x, c0.y, c0.z, c0.w, c1.x, c1.y, c1.z, c1.w};
        float dre = 0.f, dim = 0.f;
#pragma unroll
        for (int s = 0; s < 8; ++s) {
            float yr = 0.f, yi = 0.f;
#pragma unroll
            for (int t = 0; t < 8; ++t) {
                const float2 q = sQ2[w][s * 8 + t];   // broadcast
                yr += q.x * acc2[t].x - q.y * acc2[t].y;
                yi += q.x * acc2[t].y + q.y * acc2[t].x;
            }
            dre += gfr[s] * yr - gfi[s] * yi;
            dim += gfr[s] * yi + gfi[s] * yr;
        }
        float2* scr = (float2*)(out + (size_t)b * region + k * 128);
        scr[lane] = make_float2(dre * invb, dim * invb);
    }
}

// One block per b: step-size NN, diagonal Riemannian update, clamp, store.
// Reads own-region scratch (front 2048 floats) before overwriting the region.
__global__ __launch_bounds__(256) void k_finalize(
    const float* __restrict__ PhiR, const float* __restrict__ PhiI,
    const float* __restrict__ bnG, const float* __restrict__ bnB,
    const float* __restrict__ bnM, const float* __restrict__ bnV,
    const float* __restrict__ W, const float* __restrict__ Bb,
    float* __restrict__ out, int region, int cplx)
{
    const int b = blockIdx.x;
    const int tid = threadIdx.x;
    __shared__ float sIQ[128];
    __shared__ float sRed[2];
    __shared__ float sDre[64], sDim[64];

    const float* phiR = PhiR + b * 4096;
    const float* phiI = PhiI + b * 4096;
    float* outp = out + (size_t)b * region;

    // diagonal eg sum over k from own-region scratch (read BEFORE any writes)
    float er = 0.f, ei = 0.f;
    if (tid < 64) {
        const int f = tid;
#pragma unroll
        for (int kk = 0; kk < NK; ++kk) {
            const float2 dv = ((const float2*)(outp + kk * 128))[f];
            er += dv.x; ei += dv.y;
        }
    }

    // row sums of Phi (Phi @ ones): 4 threads per row
    {
        const int r = tid >> 2, pq = tid & 3;
        float sr = 0.f, si = 0.f;
        const float4* a4 = (const float4*)(phiR + r * 64 + pq * 16);
        const float4* c4 = (const float4*)(phiI + r * 64 + pq * 16);
#pragma unroll
        for (int q = 0; q < 4; ++q) {
            const float4 a = a4[q]; sr += (a.x + a.y) + (a.z + a.w);
            const float4 c = c4[q]; si += (c.x + c.y) + (c.z + c.w);
        }
        sr += __shfl_xor(sr, 1, 64); si += __shfl_xor(si, 1, 64);
        sr += __shfl_xor(sr, 2, 64); si += __shfl_xor(si, 2, 64);
        if (pq == 0) { sIQ[r] = sr; sIQ[64 + r] = si; }
    }
    __syncthreads();

    // BN -> Dense(1) -> leaky_relu
    if (tid < 128) {
        const float v = sIQ[tid];
        const float t = bnG[tid] * (v - bnM[tid]) * rsqrtf(bnV[tid] + 1e-3f) + bnB[tid];
        float contrib = t * W[tid];
#pragma unroll
        for (int o = 1; o < 64; o <<= 1) contrib += __shfl_xor(contrib, o, 64);
        if ((tid & 63) == 0) sRed[tid >> 6] = contrib;
    }
    __syncthreads();
    const float s_lin = sRed[0] + sRed[1] + Bb[0];
    const float step = (s_lin >= 0.f) ? s_lin : 0.1f * s_lin;

    // diagonal Riemannian gradient + norm (rg is exactly 0 off-diagonal)
    if (tid < 64) {
        const int f = tid;
        er *= -(1.0f / NK); ei *= -(1.0f / NK);
        const float prr = phiR[f * 65];
        const float pii = phiI[f * 65];
        const float proj = er * prr + ei * pii;     // Re(eg * conj(Phi))
        const float rr = er - proj * prr;
        const float ri = ei - proj * pii;
        float n2 = rr * rr + ri * ri;
#pragma unroll
        for (int o = 1; o < 64; o <<= 1) n2 += __shfl_xor(n2, o, 64);
        const float sc = step / sqrtf(n2);
        sDre[f] = sc * rr;
        sDim[f] = sc * ri;
    }
    __syncthreads();   // all scratch reads done; safe to overwrite region

    // elementwise: subtract diag update, magnitude clamp, store
#pragma unroll
    for (int p = 0; p < 4; ++p) {
        const int base = p * 1024 + tid * 4;
        const float4 a = *(const float4*)(phiR + base);
        const float4 c = *(const float4*)(phiI + base);
        const int row = base >> 6;
        const int col0 = base & 63;
        float re[4] = {a.x, a.y, a.z, a.w};
        float im[4] = {c.x, c.y, c.z, c.w};
#pragma unroll
        for (int q = 0; q < 4; ++q) {
            if (row == col0 + q) { re[q] -= sDre[row]; im[q] -= sDim[row]; }
            const float ab = sqrtf(re[q] * re[q] + im[q] * im[q]);
            const float den = fmaxf(ab - 1.f, 0.f) + 1.f;
            re[q] /= den; im[q] /= den;
        }
        if (cplx) {
            *(float4*)(outp + base * 2)     = make_float4(re[0], im[0], re[1], im[1]);
            *(float4*)(outp + base * 2 + 4) = make_float4(re[2], im[2], re[3], im[3]);
        } else {
            *(float4*)(outp + base) = make_float4(re[0], re[1], re[2], re[3]);
        }
    }
}

extern "C" void kernel_launch(void* const* d_in, const int* in_sizes, int n_in,
                              void* d_out, int out_size, void* d_ws, size_t ws_size,
                              hipStream_t stream) {
    const float* PhiR = (const float*)d_in[0];
    const float* PhiI = (const float*)d_in[1];
    const float* GhR  = (const float*)d_in[2];
    const float* GhI  = (const float*)d_in[3];
    const float* LamR = (const float*)d_in[4];
    const float* LamI = (const float*)d_in[5];
    const float* CR   = (const float*)d_in[6];
    const float* CI   = (const float*)d_in[7];
    const float* Beta = (const float*)d_in[8];
    const float* bnG  = (const float*)d_in[9];
    const float* bnB  = (const float*)d_in[10];
    const float* bnM  = (const float*)d_in[11];
    const float* bnV  = (const float*)d_in[12];
    const float* W    = (const float*)d_in[13];
    const float* Bb   = (const float*)d_in[14];
    float* outp = (float*)d_out;

    // out_size == B*64*64  -> real-part-only float32 layout
    // out_size == B*64*64*2 -> interleaved complex64 layout
    const int cplx = (out_size >= 3000000) ? 1 : 0;
    const int region = cplx ? 8192 : 4096;

    k_grad_diag<<<(NK * BATCH) / 4, 256, 0, stream>>>(PhiR, PhiI, GhR, GhI,
                                                      LamR, LamI, CR, CI, Beta,
                                                      outp, region);
    k_finalize<<<BATCH, 256, 0, stream>>>(PhiR, PhiI,
                                          bnG, bnB, bnM, bnV, W, Bb,
                                          outp, region, cplx);
}